// Round 14
// baseline (98.985 us; speedup 1.0000x reference)
//
#include <hip/hip_runtime.h>
#include <math.h>

#define B_ 8
#define N_ 2048
#define NT_ (B_*N_)          // 16384 rows
#define OUTSZ (NT_*64)       // 1048576 elements per output tensor

// ---- workspace layout (float offsets) ----
#define WS_ASRC  0
#define WS_ADST  (WS_ASRC + NT_)
#define WS_WT    (WS_ADST + NT_)         // [128][256] fused gate weights (transposed)
#define WS_BB    (WS_WT + 128*256)       // [256] combined gate bias
#define WS_WOT   (WS_BB + 256)           // [128][64] Wout transposed
#define WS_XH    (WS_WOT + 128*64)       // x_hidden f32 [NT_][64]
// WhT bf16 [B][64][N] lives in d_out[0 .. 524288 floats) -- dead until k5 overwrites.

typedef float f32x4 __attribute__((ext_vector_type(4)));
typedef float f32x2 __attribute__((ext_vector_type(2)));
typedef __bf16 bf16x8 __attribute__((ext_vector_type(8)));
typedef __bf16 bf16x4 __attribute__((ext_vector_type(4)));

__device__ __forceinline__ float lrelu2(float x) { return x > 0.f ? x : 2.f * x; }
__device__ __forceinline__ float f4get(const float4& v, int k) { return k==0?v.x:(k==1?v.y:(k==2?v.z:v.w)); }

// ---------------- K1 (+fused weight prep): Wh = x@W -> WhT bf16, a_src/a_dst ----------------
__global__ __launch_bounds__(256) void k1_wh(const float* __restrict__ x, const float* __restrict__ W,
                                             const float* __restrict__ a, float* __restrict__ ws,
                                             __bf16* __restrict__ whT,
                                             const float* Wf, const float* Wi, const float* Wo, const float* Wc,
                                             const float* Uf, const float* Ui, const float* Uo, const float* Uc,
                                             const float* bWf, const float* bWi, const float* bWo, const float* bWc,
                                             const float* bUf, const float* bUi, const float* bUo, const float* bUc,
                                             const float* Wout)
{
    __shared__ float xl[64 * 68];
    __shared__ float Wl[64 * 68];
    int t = threadIdx.x;
    if (blockIdx.x >= 256) {
        int idx = (blockIdx.x - 256) * 256 + t;
        if (idx < 128 * 256) {
            int k = idx >> 8, o = idx & 255;
            int g = o >> 6, u = o & 63;
            const float* Wg = (g == 0) ? Wf : (g == 1) ? Wi : (g == 2) ? Wo : Wc;
            const float* Ug = (g == 0) ? Uf : (g == 1) ? Ui : (g == 2) ? Uo : Uc;
            ws[WS_WT + idx] = (k < 64) ? Wg[u * 64 + k] : Ug[u * 64 + (k - 64)];
        } else if (idx < 128 * 256 + 256) {
            int o = idx - 128 * 256;
            int g = o >> 6, u = o & 63;
            const float* bW = (g == 0) ? bWf : (g == 1) ? bWi : (g == 2) ? bWo : bWc;
            const float* bU = (g == 0) ? bUf : (g == 1) ? bUi : (g == 2) ? bUo : bUc;
            ws[WS_BB + o] = bW[u] + bU[u];
        } else if (idx < 128 * 256 + 256 + 128 * 64) {
            int j = idx - (128 * 256 + 256);
            int k = j >> 6, u = j & 63;
            ws[WS_WOT + j] = Wout[u * 128 + k];   // WoutT[k][u]
        }
        return;
    }
    int i0 = blockIdx.x * 64;
    #pragma unroll
    for (int it = 0; it < 4; ++it) {
        int f = t + 256 * it;
        int r = f >> 4, q = f & 15;
        *(float4*)&xl[r * 68 + q * 4] = *(const float4*)&x[i0 * 64 + f * 4];
        *(float4*)&Wl[r * 68 + q * 4] = *(const float4*)&W[f * 4];
    }
    __syncthreads();
    int cg = t & 15, rg = t >> 4;
    int c0 = cg * 4, r0 = rg * 4;
    float acc[4][4] = {};
    #pragma unroll
    for (int d0 = 0; d0 < 64; d0 += 4) {
        float4 wv[4], xv[4];
        #pragma unroll
        for (int k = 0; k < 4; ++k) wv[k] = *(float4*)&Wl[(d0 + k) * 68 + c0];
        #pragma unroll
        for (int ri = 0; ri < 4; ++ri) xv[ri] = *(float4*)&xl[(r0 + ri) * 68 + d0];
        #pragma unroll
        for (int ri = 0; ri < 4; ++ri)
            #pragma unroll
            for (int k = 0; k < 4; ++k) {
                float xs = f4get(xv[ri], k);
                acc[ri][0] += xs * wv[k].x; acc[ri][1] += xs * wv[k].y;
                acc[ri][2] += xs * wv[k].z; acc[ri][3] += xs * wv[k].w;
            }
    }
    int b = i0 >> 11;
    int rowb0 = (i0 & 2047) + r0;
    #pragma unroll
    for (int cj = 0; cj < 4; ++cj) {
        bf16x4 v;
        v[0] = (__bf16)acc[0][cj]; v[1] = (__bf16)acc[1][cj];
        v[2] = (__bf16)acc[2][cj]; v[3] = (__bf16)acc[3][cj];
        *(bf16x4*)&whT[((size_t)(b * 64 + c0 + cj)) * N_ + rowb0] = v;
    }
    float4 a0 = *(const float4*)&a[c0];
    float4 a1 = *(const float4*)&a[64 + c0];
    #pragma unroll
    for (int ri = 0; ri < 4; ++ri) {
        int row = i0 + r0 + ri;
        float s0 = acc[ri][0]*a0.x + acc[ri][1]*a0.y + acc[ri][2]*a0.z + acc[ri][3]*a0.w;
        float s1 = acc[ri][0]*a1.x + acc[ri][1]*a1.y + acc[ri][2]*a1.z + acc[ri][3]*a1.w;
        #pragma unroll
        for (int m = 1; m < 16; m <<= 1) { s0 += __shfl_xor(s0, m, 64); s1 += __shfl_xor(s1, m, 64); }
        if (cg == 0) { ws[WS_ASRC + row] = s0; ws[WS_ADST + row] = s1; }
    }
}

// ---------------- K2v11: rows-fixed, all-j, LDS-staged adj+B, NO partials ----------------
// Block = 16 rows (1024 blocks, 3/CU). 4 waves x 64-j lanes within each 256-j chunk; 8 chunks.
// Persistent register accumulators + denominators -> ONE combine at end -> direct XH write.
// adj staged coalesced -> dbuf LDS; B (whT) staged whole-wave-contiguous (512B/instr, L2) into
// single-buffer Bl; frags via ds_read. adst broadcast-loaded to regs. lsa ALIASES Bl (LDS 50.5KB).
__global__ __launch_bounds__(256) void k2v11(const float* __restrict__ adj,
                                             const __bf16* __restrict__ whT,
                                             float* __restrict__ ws)
{
    __shared__ __align__(16) char smem_[34304 + 17152 + 256 + 16];
    __bf16 (*Bl)[268]        = (__bf16(*)[268])smem_;                      // [64][268]
    __bf16 (*adjt)[16][268]  = (__bf16(*)[16][268])(smem_ + 34304);        // [2][16][268]
    float (*lsd)[16]         = (float(*)[16])(smem_ + 34304 + 17152);      // [4][16]
    float* gred              = (float*)(smem_ + 34304 + 17152 + 256);      // [4]
    float (*lsa)[16][68]     = (float(*)[16][68])smem_;                    // alias over Bl (end only)

    int tid = threadIdx.x;
    int lane = tid & 63, w = tid >> 6;        // 4 waves
    int r = lane & 15, g = lane >> 4;
    int row0 = blockIdx.x * 16;
    int b = row0 >> 11;

    // per-batch gmax: block-local reduce over ADST (L2-resident)
    {
        float gm = -3.0e38f;
        for (int i = tid; i < N_; i += 256) gm = fmaxf(gm, ws[WS_ADST + b * N_ + i]);
        #pragma unroll
        for (int m_ = 1; m_ < 64; m_ <<= 1) gm = fmaxf(gm, __shfl_xor(gm, m_, 64));
        if (lane == 0) gred[w] = gm;
    }
    __syncthreads();
    float gmax = fmaxf(fmaxf(gred[0], gred[1]), fmaxf(gred[2], gred[3]));

    // loop-invariant softmax constants (rows fixed for whole block)
    float as = ws[WS_ASRC + row0 + r];
    float M  = lrelu2(as + gmax);
    float c1 = __expf(as - M);
    float c2 = __expf(2.f * as - M);
    float thr = __expf(-as);

    f32x2 sregB[16];
    f32x4 sregA[4];
    f32x4 sregD[2][2][2];

#define SLOADB(CC)                                                                          \
    { _Pragma("unroll")                                                                     \
      for (int i = 0; i < 16; ++i)                                                          \
          sregB[i] = *(const f32x2*)&whT[(size_t)(b * 64 + w * 16 + i) * N_ + (CC) * 256 + lane * 4]; }
#define SWRITEB()                                                                           \
    { _Pragma("unroll")                                                                     \
      for (int i = 0; i < 16; ++i)                                                          \
          *(f32x2*)&Bl[w * 16 + i][lane * 4] = sregB[i]; }
#define SLOADA(CC)                                                                          \
    { _Pragma("unroll")                                                                     \
      for (int i = 0; i < 4; ++i)                                                           \
          sregA[i] = *(const f32x4*)&adj[(size_t)(row0 + w * 4 + i) * N_ + (CC) * 256 + lane * 4]; }
#define SWRITEA(S)                                                                          \
    { _Pragma("unroll")                                                                     \
      for (int i = 0; i < 4; ++i) {                                                         \
          bf16x4 bv;                                                                        \
          bv[0] = (__bf16)sregA[i][0]; bv[1] = (__bf16)sregA[i][1];                         \
          bv[2] = (__bf16)sregA[i][2]; bv[3] = (__bf16)sregA[i][3];                         \
          *(bf16x4*)&adjt[S][w * 4 + i][lane * 4] = bv; } }
#define SLOADD(CC, S)                                                                       \
    { _Pragma("unroll")                                                                     \
      for (int ks = 0; ks < 2; ++ks) {                                                      \
          sregD[S][ks][0] = *(const f32x4*)&ws[WS_ADST + b * N_ + (CC) * 256 + w * 64 + ks * 32 + g * 8];      \
          sregD[S][ks][1] = *(const f32x4*)&ws[WS_ADST + b * N_ + (CC) * 256 + w * 64 + ks * 32 + g * 8 + 4]; } }
#define BARR  { asm volatile("s_waitcnt lgkmcnt(0)" ::: "memory");                          \
                __builtin_amdgcn_s_barrier();                                               \
                asm volatile("" ::: "memory"); }

    f32x4 acc[4] = {{0.f,0.f,0.f,0.f},{0.f,0.f,0.f,0.f},{0.f,0.f,0.f,0.f},{0.f,0.f,0.f,0.f}};
    float dsum = 0.f;

    // prologue: chunk 0 fully staged
    SLOADB(0); SLOADA(0); SLOADD(0, 0);
    SWRITEB(); SWRITEA(0);
    BARR;

    #pragma unroll
    for (int cc = 0; cc < 8; ++cc) {
        const int s = cc & 1;
        // 1. issue next-chunk loads to regs (HBM adj + L2 B + adst broadcast)
        if (cc < 7) { SLOADB(cc + 1); SLOADA(cc + 1); SLOADD(cc + 1, s ^ 1); }
        // 2. compute chunk cc (pure LDS + regs)
        #pragma unroll
        for (int ks = 0; ks < 2; ++ks) {
            bf16x8 at = *(const bf16x8*)&adjt[s][r][w * 64 + ks * 32 + g * 8];
            bf16x8 af;
            float ds_ = 0.f;
            #pragma unroll
            for (int e = 0; e < 8; ++e) {
                float dd = sregD[s][ks][e < 4 ? 0 : 1][e & 3];
                float E = __expf(dd);
                float p = (E > thr) ? c1 * E : (c2 * E) * E;
                p = ((float)at[e] > 0.f) ? p : 0.f;
                ds_ += p;
                af[e] = (__bf16)p;
            }
            dsum += ds_;
            #pragma unroll
            for (int n = 0; n < 4; ++n) {
                bf16x8 bfrg = *(const bf16x8*)&Bl[n * 16 + r][w * 64 + ks * 32 + g * 8];
                acc[n] = __builtin_amdgcn_mfma_f32_16x16x32_bf16(af, bfrg, acc[n], 0, 0, 0);
            }
        }
        // 3. all waves done reading Bl/adjt for chunk cc
        BARR;
        // 4. stage chunk cc+1 into LDS (vmcnt waits auto-inserted for sreg deps)
        if (cc < 7) { SWRITEB(); SWRITEA(s ^ 1); }
        // 5. staged data visible to all waves
        BARR;
    }

    // denominator: sum the 4 k-groups of each row within the wave
    dsum += __shfl_xor(dsum, 16, 64);
    dsum += __shfl_xor(dsum, 32, 64);

    // final combine: lsa aliases Bl (dead); loop's trailing BARR already synced all waves
    #pragma unroll
    for (int n = 0; n < 4; ++n)
        #pragma unroll
        for (int i = 0; i < 4; ++i)
            lsa[w][g * 4 + i][n * 16 + r] = acc[n][i];
    if (g == 0) lsd[w][r] = dsum;
    BARR;
    {
        int rl = tid >> 4, h0 = (tid & 15) * 4;
        float4 sv = make_float4(0.f, 0.f, 0.f, 0.f);
        #pragma unroll
        for (int w2 = 0; w2 < 4; ++w2) {
            float4 q = *(const float4*)&lsa[w2][rl][h0];
            sv.x += q.x; sv.y += q.y; sv.z += q.z; sv.w += q.w;
        }
        float dtot = lsd[0][rl] + lsd[1][rl] + lsd[2][rl] + lsd[3][rl];
        float inv = 1.f / dtot;
        float4 o;
        o.x = sv.x * inv; o.x = o.x > 0.f ? o.x : expm1f(o.x);
        o.y = sv.y * inv; o.y = o.y > 0.f ? o.y : expm1f(o.y);
        o.z = sv.z * inv; o.z = o.z > 0.f ? o.z : expm1f(o.z);
        o.w = sv.w * inv; o.w = o.w > 0.f ? o.w : expm1f(o.w);
        *(float4*)&ws[WS_XH + (size_t)(row0 + rl) * 64 + h0] = o;
    }
#undef SLOADB
#undef SWRITEB
#undef SLOADA
#undef SWRITEA
#undef SLOADD
#undef BARR
}

// ---------------- K3: LSTM gates + cell update. 16 rows/block ----------------
__global__ __launch_bounds__(256) void k3_lstm(const float* __restrict__ x, const float* __restrict__ c,
                                               const float* __restrict__ h, const float* __restrict__ ws,
                                               float* __restrict__ out)
{
    __shared__ float Al[16 * 132];   // [row][k]: k<64 = h, k>=64 = x
    __shared__ float gl[16 * 260];   // gate pre-activations [row][256]
    int t = threadIdx.x;
    int base = blockIdx.x * 16;
    {
        int r = t >> 4, k0 = (t & 15) * 8;
        const float* src = (k0 < 64) ? &h[(base + r) * 64 + k0] : &x[(base + r) * 64 + (k0 - 64)];
        *(float4*)&Al[r * 132 + k0]     = *(const float4*)&src[0];
        *(float4*)&Al[r * 132 + k0 + 4] = *(const float4*)&src[4];
    }
    __syncthreads();
    int og = t & 63, rg = t >> 6;
    int o0 = og * 4;
    const float* WT = &ws[WS_WT];
    float acc[4][4] = {};
    #pragma unroll
    for (int k0 = 0; k0 < 128; k0 += 4) {
        float4 wv[4], av[4];
        #pragma unroll
        for (int kk = 0; kk < 4; ++kk) wv[kk] = *(const float4*)&WT[(k0 + kk) * 256 + o0];
        #pragma unroll
        for (int rr = 0; rr < 4; ++rr) av[rr] = *(float4*)&Al[(rg + 4 * rr) * 132 + k0];
        #pragma unroll
        for (int rr = 0; rr < 4; ++rr)
            #pragma unroll
            for (int kk = 0; kk < 4; ++kk) {
                float as = f4get(av[rr], kk);
                acc[rr][0] += as * wv[kk].x; acc[rr][1] += as * wv[kk].y;
                acc[rr][2] += as * wv[kk].z; acc[rr][3] += as * wv[kk].w;
            }
    }
    float4 bbv = *(const float4*)&ws[WS_BB + o0];
    #pragma unroll
    for (int rr = 0; rr < 4; ++rr) {
        int r = rg + 4 * rr;
        *(float4*)&gl[r * 260 + o0] = make_float4(acc[rr][0] + bbv.x, acc[rr][1] + bbv.y,
                                                  acc[rr][2] + bbv.z, acc[rr][3] + bbv.w);
    }
    __syncthreads();
    int u = t & 63, rq = t >> 6;
    #pragma unroll
    for (int pp = 0; pp < 4; ++pp) {
        int r = rq + 4 * pp;
        float gf = gl[r * 260 + u];
        float gi = gl[r * 260 + 64 + u];
        float go = gl[r * 260 + 128 + u];
        float gc = gl[r * 260 + 192 + u];
        float fg = 1.f / (1.f + __expf(-gf));
        float ig = 1.f / (1.f + __expf(-gi));
        float oo = 1.f / (1.f + __expf(-go));
        float ch = tanhf(gc);
        float cv = c[(base + r) * 64 + u];
        float ct = fg * cv + ig * ch;
        float ht = oo * fmaxf(ct, 0.f);
        out[OUTSZ + (base + r) * 64 + u] = ht;
        out[2 * OUTSZ + (base + r) * 64 + u] = ct;
    }
}

// ---------------- K5: output = relu([x_hidden | h_t] @ WoutT + bout). 64 rows/block ----------------
__global__ __launch_bounds__(256) void k5_out(const float* __restrict__ ws, const float* __restrict__ bout,
                                              float* __restrict__ out)
{
    __shared__ float Al[64 * 132];
    int t = threadIdx.x;
    int base = blockIdx.x * 64;
    const float* xh = &ws[WS_XH];
    const float* ht = &out[OUTSZ];
    #pragma unroll
    for (int it = 0; it < 8; ++it) {
        int f = t + 256 * it;
        int r = f >> 5, q = f & 31;
        int k0 = q * 4;
        float4 v;
        if (k0 < 64) v = *(const float4*)&xh[(size_t)(base + r) * 64 + k0];
        else         v = *(const float4*)&ht[(size_t)(base + r) * 64 + (k0 - 64)];
        *(float4*)&Al[r * 132 + k0] = v;
    }
    __syncthreads();
    int cg = t & 15, rgG = t >> 4;
    int c0 = cg * 4, r0 = rgG * 4;
    const float* WT = &ws[WS_WOT];
    float acc[4][4] = {};
    #pragma unroll
    for (int k0 = 0; k0 < 128; k0 += 4) {
        float4 wv[4], av[4];
        #pragma unroll
        for (int kk = 0; kk < 4; ++kk) wv[kk] = *(const float4*)&WT[(k0 + kk) * 64 + c0];
        #pragma unroll
        for (int ri = 0; ri < 4; ++ri) av[ri] = *(float4*)&Al[(r0 + ri) * 132 + k0];
        #pragma unroll
        for (int ri = 0; ri < 4; ++ri)
            #pragma unroll
            for (int kk = 0; kk < 4; ++kk) {
                float as = f4get(av[ri], kk);
                acc[ri][0] += as * wv[kk].x; acc[ri][1] += as * wv[kk].y;
                acc[ri][2] += as * wv[kk].z; acc[ri][3] += as * wv[kk].w;
            }
    }
    float4 bo = *(const float4*)&bout[c0];
    #pragma unroll
    for (int ri = 0; ri < 4; ++ri) {
        int row = base + r0 + ri;
        float4 o;
        o.x = fmaxf(acc[ri][0] + bo.x, 0.f);
        o.y = fmaxf(acc[ri][1] + bo.y, 0.f);
        o.z = fmaxf(acc[ri][2] + bo.z, 0.f);
        o.w = fmaxf(acc[ri][3] + bo.w, 0.f);
        *(float4*)&out[row * 64 + c0] = o;
    }
}

extern "C" void kernel_launch(void* const* d_in, const int* in_sizes, int n_in,
                              void* d_out, int out_size, void* d_ws, size_t ws_size,
                              hipStream_t stream)
{
    const float* x    = (const float*)d_in[0];
    const float* adj  = (const float*)d_in[1];
    const float* c    = (const float*)d_in[2];
    const float* h    = (const float*)d_in[3];
    const float* W    = (const float*)d_in[4];
    const float* a    = (const float*)d_in[5];
    const float* Wf   = (const float*)d_in[6];
    const float* bWf  = (const float*)d_in[7];
    const float* Wi   = (const float*)d_in[8];
    const float* bWi  = (const float*)d_in[9];
    const float* Wo   = (const float*)d_in[10];
    const float* bWo  = (const float*)d_in[11];
    const float* Wc   = (const float*)d_in[12];
    const float* bWc  = (const float*)d_in[13];
    const float* Uf   = (const float*)d_in[14];
    const float* bUf  = (const float*)d_in[15];
    const float* Ui   = (const float*)d_in[16];
    const float* bUi  = (const float*)d_in[17];
    const float* Uo   = (const float*)d_in[18];
    const float* bUo  = (const float*)d_in[19];
    const float* Uc   = (const float*)d_in[20];
    const float* bUc  = (const float*)d_in[21];
    const float* Wout = (const float*)d_in[22];
    const float* bout = (const float*)d_in[23];
    float* out = (float*)d_out;
    float* ws  = (float*)d_ws;
    __bf16* whT = (__bf16*)out;   // WhT bf16 scratch in d_out segment 0; k5 overwrites last

    k1_wh<<<417, 256, 0, stream>>>(x, W, a, ws, whT,
                                   Wf, Wi, Wo, Wc, Uf, Ui, Uo, Uc,
                                   bWf, bWi, bWo, bWc, bUf, bUi, bUo, bUc, Wout);
    k3_lstm<<<NT_ / 16, 256, 0, stream>>>(x, c, h, ws, out);
    k2v11<<<NT_ / 16, 256, 0, stream>>>(adj, whT, ws);
    k5_out<<<NT_ / 64, 256, 0, stream>>>(ws, bout, out);
}

// Round 15
// 97.359 us; speedup vs baseline: 1.0167x; 1.0167x over previous
//
#include <hip/hip_runtime.h>
#include <math.h>

#define B_ 8
#define N_ 2048
#define NT_ (B_*N_)          // 16384 rows
#define OUTSZ (NT_*64)       // 1048576 elements per output tensor

// ---- workspace layout (float offsets) ----
#define WS_ASRC  0
#define WS_ADST  (WS_ASRC + NT_)
#define WS_WT    (WS_ADST + NT_)         // [128][256] fused gate weights (transposed)
#define WS_BB    (WS_WT + 128*256)       // [256] combined gate bias
#define WS_WOT   (WS_BB + 256)           // [128][64] Wout transposed
#define WS_PD    (WS_WOT + 128*64)       // [8][NT_] partial denominators
#define WS_PN    (WS_PD + 8*NT_)         // [8][NT_][64] partial numerators (32 MB)
#define WS_MASK  (WS_PN + 8*NT_*64)      // u32[NT_][64] adj bitmask (4 MB)
// WhT bf16 [B][64][N] lives in d_out[0 .. 524288 floats) -- dead until k5 overwrites.

typedef float f32x4 __attribute__((ext_vector_type(4)));
typedef __bf16 bf16x8 __attribute__((ext_vector_type(8)));
typedef __bf16 bf16x4 __attribute__((ext_vector_type(4)));

__device__ __forceinline__ float lrelu2(float x) { return x > 0.f ? x : 2.f * x; }
__device__ __forceinline__ float f4get(const float4& v, int k) { return k==0?v.x:(k==1?v.y:(k==2?v.z:v.w)); }

// ---------------- Kpack: adj (134 MB) -> bitmask (4 MB). PURE LINEAR STREAM (85% BW proven R10). ----
__global__ __launch_bounds__(256) void kpack(const float* __restrict__ adj, unsigned* __restrict__ mask)
{
    size_t base = ((size_t)blockIdx.x * 256 + threadIdx.x) * 32;
    const float* p = adj + base;
    unsigned bits = 0u;
    #pragma unroll
    for (int q = 0; q < 8; ++q) {
        float4 v = *(const float4*)&p[q * 4];
        bits |= (v.x > 0.f ? 1u : 0u) << (q * 4);
        bits |= (v.y > 0.f ? 1u : 0u) << (q * 4 + 1);
        bits |= (v.z > 0.f ? 1u : 0u) << (q * 4 + 2);
        bits |= (v.w > 0.f ? 1u : 0u) << (q * 4 + 3);
    }
    mask[base >> 5] = bits;
}

// ---------------- K1 (+fused weight prep): Wh = x@W -> WhT bf16, a_src/a_dst ----------------
__global__ __launch_bounds__(256) void k1_wh(const float* __restrict__ x, const float* __restrict__ W,
                                             const float* __restrict__ a, float* __restrict__ ws,
                                             __bf16* __restrict__ whT,
                                             const float* Wf, const float* Wi, const float* Wo, const float* Wc,
                                             const float* Uf, const float* Ui, const float* Uo, const float* Uc,
                                             const float* bWf, const float* bWi, const float* bWo, const float* bWc,
                                             const float* bUf, const float* bUi, const float* bUo, const float* bUc,
                                             const float* Wout)
{
    __shared__ float xl[64 * 68];
    __shared__ float Wl[64 * 68];
    int t = threadIdx.x;
    if (blockIdx.x >= 256) {
        int idx = (blockIdx.x - 256) * 256 + t;
        if (idx < 128 * 256) {
            int k = idx >> 8, o = idx & 255;
            int g = o >> 6, u = o & 63;
            const float* Wg = (g == 0) ? Wf : (g == 1) ? Wi : (g == 2) ? Wo : Wc;
            const float* Ug = (g == 0) ? Uf : (g == 1) ? Ui : (g == 2) ? Uo : Uc;
            ws[WS_WT + idx] = (k < 64) ? Wg[u * 64 + k] : Ug[u * 64 + (k - 64)];
        } else if (idx < 128 * 256 + 256) {
            int o = idx - 128 * 256;
            int g = o >> 6, u = o & 63;
            const float* bW = (g == 0) ? bWf : (g == 1) ? bWi : (g == 2) ? bWo : bWc;
            const float* bU = (g == 0) ? bUf : (g == 1) ? bUi : (g == 2) ? bUo : bUc;
            ws[WS_BB + o] = bW[u] + bU[u];
        } else if (idx < 128 * 256 + 256 + 128 * 64) {
            int j = idx - (128 * 256 + 256);
            int k = j >> 6, u = j & 63;
            ws[WS_WOT + j] = Wout[u * 128 + k];   // WoutT[k][u]
        }
        return;
    }
    int i0 = blockIdx.x * 64;
    #pragma unroll
    for (int it = 0; it < 4; ++it) {
        int f = t + 256 * it;
        int r = f >> 4, q = f & 15;
        *(float4*)&xl[r * 68 + q * 4] = *(const float4*)&x[i0 * 64 + f * 4];
        *(float4*)&Wl[r * 68 + q * 4] = *(const float4*)&W[f * 4];
    }
    __syncthreads();
    int cg = t & 15, rg = t >> 4;
    int c0 = cg * 4, r0 = rg * 4;
    float acc[4][4] = {};
    #pragma unroll
    for (int d0 = 0; d0 < 64; d0 += 4) {
        float4 wv[4], xv[4];
        #pragma unroll
        for (int k = 0; k < 4; ++k) wv[k] = *(float4*)&Wl[(d0 + k) * 68 + c0];
        #pragma unroll
        for (int ri = 0; ri < 4; ++ri) xv[ri] = *(float4*)&xl[(r0 + ri) * 68 + d0];
        #pragma unroll
        for (int ri = 0; ri < 4; ++ri)
            #pragma unroll
            for (int k = 0; k < 4; ++k) {
                float xs = f4get(xv[ri], k);
                acc[ri][0] += xs * wv[k].x; acc[ri][1] += xs * wv[k].y;
                acc[ri][2] += xs * wv[k].z; acc[ri][3] += xs * wv[k].w;
            }
    }
    int b = i0 >> 11;
    int rowb0 = (i0 & 2047) + r0;
    #pragma unroll
    for (int cj = 0; cj < 4; ++cj) {
        bf16x4 v;
        v[0] = (__bf16)acc[0][cj]; v[1] = (__bf16)acc[1][cj];
        v[2] = (__bf16)acc[2][cj]; v[3] = (__bf16)acc[3][cj];
        *(bf16x4*)&whT[((size_t)(b * 64 + c0 + cj)) * N_ + rowb0] = v;
    }
    float4 a0 = *(const float4*)&a[c0];
    float4 a1 = *(const float4*)&a[64 + c0];
    #pragma unroll
    for (int ri = 0; ri < 4; ++ri) {
        int row = i0 + r0 + ri;
        float s0 = acc[ri][0]*a0.x + acc[ri][1]*a0.y + acc[ri][2]*a0.z + acc[ri][3]*a0.w;
        float s1 = acc[ri][0]*a1.x + acc[ri][1]*a1.y + acc[ri][2]*a1.z + acc[ri][3]*a1.w;
        #pragma unroll
        for (int m = 1; m < 16; m <<= 1) { s0 += __shfl_xor(s0, m, 64); s1 += __shfl_xor(s1, m, 64); }
        if (cg == 0) { ws[WS_ASRC + row] = s0; ws[WS_ADST + row] = s1; }
    }
}

// ---------------- K2v12: j-resident MFMA GEMM, MASK-driven (zero HBM, zero LDS staging) ----------------
// Block = (jr of 8, 128-row slab), 4 waves x fixed 64-j window. B-frags + Ej register-resident
// (R13 proven). A-data per tile = ONE uint2 mask load per lane (128 B/wave, L2-resident 4 MB),
// depth-2 prefetch via a 3-slot statically-indexed ring. p = bit ? (E>thr ? c1*E : c2*E^2) : 0
// (R10 proven). PN/PD partial outputs as R13.
__global__ __launch_bounds__(256) void k2v12(const unsigned* __restrict__ mask,
                                             const __bf16* __restrict__ whT,
                                             float* __restrict__ ws)
{
    __shared__ float lsa[4][16][68];
    __shared__ float lsd[4][16];
    __shared__ float gred[4];
    int tid = threadIdx.x;
    int lane = tid & 63, w = tid >> 6;        // 4 waves
    int r = lane & 15, g = lane >> 4;
    int jr = blockIdx.x & 7;
    int rslab = blockIdx.x >> 3;              // 0..127
    int b = rslab >> 4;
    int row_base = rslab * 128;
    int jbeg = jr * 256 + w * 64;
    int jw0 = jr * 8 + w * 2;                 // mask word base for this wave's j-window

    // per-batch gmax: block-local reduce over ADST (L2-resident). R13 proven.
    {
        float gm = -3.0e38f;
        for (int i = tid; i < N_; i += 256) gm = fmaxf(gm, ws[WS_ADST + b * N_ + i]);
        #pragma unroll
        for (int m_ = 1; m_ < 64; m_ <<= 1) gm = fmaxf(gm, __shfl_xor(gm, m_, 64));
        if (lane == 0) gred[w] = gm;
    }
    __syncthreads();
    float gmax = fmaxf(fmaxf(gred[0], gred[1]), fmaxf(gred[2], gred[3]));

    // loop-invariant B-frags: lane -> col h = n*16 + r, k-window = ks*32 + g*8
    bf16x8 bfr[2][4];
    #pragma unroll
    for (int ks = 0; ks < 2; ++ks)
        #pragma unroll
        for (int n = 0; n < 4; ++n)
            bfr[ks][n] = *(const bf16x8*)&whT[(size_t)(b * 64 + n * 16 + r) * N_ + jbeg + ks * 32 + g * 8];
    // loop-invariant Ej = exp(adst_j) registers
    float ejr[2][8];
    #pragma unroll
    for (int ks = 0; ks < 2; ++ks) {
        float4 d0 = *(const float4*)&ws[WS_ADST + b * N_ + jbeg + ks * 32 + g * 8];
        float4 d1 = *(const float4*)&ws[WS_ADST + b * N_ + jbeg + ks * 32 + g * 8 + 4];
        ejr[ks][0]=__expf(d0.x); ejr[ks][1]=__expf(d0.y); ejr[ks][2]=__expf(d0.z); ejr[ks][3]=__expf(d0.w);
        ejr[ks][4]=__expf(d1.x); ejr[ks][5]=__expf(d1.y); ejr[ks][6]=__expf(d1.z); ejr[ks][7]=__expf(d1.w);
    }
    // all 8 per-tile asrc scalars hoisted (statically indexed) -- R13 proven
    float asv8[8];
    #pragma unroll
    for (int tt = 0; tt < 8; ++tt)
        asv8[tt] = ws[WS_ASRC + row_base + tt * 16 + r];

    uint2 mreg[3];
#define MLOAD(T, S)  mreg[S] = *(const uint2*)&mask[(size_t)(row_base + (T) * 16 + r) * 64 + jw0];

    MLOAD(0, 0);
    MLOAD(1, 1);

    #pragma unroll
    for (int t = 0; t < 8; ++t) {
        const int s = t % 3;
        if (t + 2 < 8) { MLOAD(t + 2, (t + 2) % 3); }
        float as = asv8[t];
        float M  = lrelu2(as + gmax);
        float c1 = __expf(as - M);
        float c2 = __expf(2.f * as - M);
        float thr = __expf(-as);
        f32x4 acc[4] = {{0.f,0.f,0.f,0.f},{0.f,0.f,0.f,0.f},{0.f,0.f,0.f,0.f},{0.f,0.f,0.f,0.f}};
        float dsum = 0.f;
        #pragma unroll
        for (int ks = 0; ks < 2; ++ks) {
            unsigned word = ks ? mreg[s].y : mreg[s].x;
            unsigned m8 = (word >> (g * 8)) & 0xffu;
            bf16x8 af;
            float ds_ = 0.f;
            #pragma unroll
            for (int e = 0; e < 8; ++e) {
                float E = ejr[ks][e];
                float p = (E > thr) ? c1 * E : (c2 * E) * E;
                p = ((m8 >> e) & 1u) ? p : 0.f;
                ds_ += p;
                af[e] = (__bf16)p;
            }
            dsum += ds_;
            #pragma unroll
            for (int n = 0; n < 4; ++n)
                acc[n] = __builtin_amdgcn_mfma_f32_16x16x32_bf16(af, bfr[ks][n], acc[n], 0, 0, 0);
        }
        dsum += __shfl_xor(dsum, 16, 64);
        dsum += __shfl_xor(dsum, 32, 64);
        // wave partial -> LDS
        #pragma unroll
        for (int n = 0; n < 4; ++n)
            #pragma unroll
            for (int i = 0; i < 4; ++i)
                lsa[w][g * 4 + i][n * 16 + r] = acc[n][i];
        if (g == 0) lsd[w][r] = dsum;
        // raw barrier: LDS visibility only; mask prefetches stay in flight
        asm volatile("s_waitcnt lgkmcnt(0)" ::: "memory");
        __builtin_amdgcn_s_barrier();
        asm volatile("" ::: "memory");
        // combine 4 wave-slices -> global partial (jr slice)
        {
            int rl = tid >> 4, h0 = (tid & 15) * 4;
            float4 sv = make_float4(0.f, 0.f, 0.f, 0.f);
            #pragma unroll
            for (int w2 = 0; w2 < 4; ++w2) {
                float4 q = *(const float4*)&lsa[w2][rl][h0];
                sv.x += q.x; sv.y += q.y; sv.z += q.z; sv.w += q.w;
            }
            int row0 = row_base + t * 16;
            *(float4*)&ws[WS_PN + ((size_t)jr * NT_ + row0 + rl) * 64 + h0] = sv;
            if (tid < 16)
                ws[WS_PD + jr * NT_ + row0 + tid] =
                    lsd[0][tid] + lsd[1][tid] + lsd[2][tid] + lsd[3][tid];
        }
        asm volatile("s_waitcnt lgkmcnt(0)" ::: "memory");
        __builtin_amdgcn_s_barrier();
        asm volatile("" ::: "memory");
    }
#undef MLOAD
}

// ---------------- K3: LSTM gates + cell update. 16 rows/block ----------------
__global__ __launch_bounds__(256) void k3_lstm(const float* __restrict__ x, const float* __restrict__ c,
                                               const float* __restrict__ h, const float* __restrict__ ws,
                                               float* __restrict__ out)
{
    __shared__ float Al[16 * 132];   // [row][k]: k<64 = h, k>=64 = x
    __shared__ float gl[16 * 260];   // gate pre-activations [row][256]
    int t = threadIdx.x;
    int base = blockIdx.x * 16;
    {
        int r = t >> 4, k0 = (t & 15) * 8;
        const float* src = (k0 < 64) ? &h[(base + r) * 64 + k0] : &x[(base + r) * 64 + (k0 - 64)];
        *(float4*)&Al[r * 132 + k0]     = *(const float4*)&src[0];
        *(float4*)&Al[r * 132 + k0 + 4] = *(const float4*)&src[4];
    }
    __syncthreads();
    int og = t & 63, rg = t >> 6;
    int o0 = og * 4;
    const float* WT = &ws[WS_WT];
    float acc[4][4] = {};
    #pragma unroll
    for (int k0 = 0; k0 < 128; k0 += 4) {
        float4 wv[4], av[4];
        #pragma unroll
        for (int kk = 0; kk < 4; ++kk) wv[kk] = *(const float4*)&WT[(k0 + kk) * 256 + o0];
        #pragma unroll
        for (int rr = 0; rr < 4; ++rr) av[rr] = *(float4*)&Al[(rg + 4 * rr) * 132 + k0];
        #pragma unroll
        for (int rr = 0; rr < 4; ++rr)
            #pragma unroll
            for (int kk = 0; kk < 4; ++kk) {
                float as = f4get(av[rr], kk);
                acc[rr][0] += as * wv[kk].x; acc[rr][1] += as * wv[kk].y;
                acc[rr][2] += as * wv[kk].z; acc[rr][3] += as * wv[kk].w;
            }
    }
    float4 bbv = *(const float4*)&ws[WS_BB + o0];
    #pragma unroll
    for (int rr = 0; rr < 4; ++rr) {
        int r = rg + 4 * rr;
        *(float4*)&gl[r * 260 + o0] = make_float4(acc[rr][0] + bbv.x, acc[rr][1] + bbv.y,
                                                  acc[rr][2] + bbv.z, acc[rr][3] + bbv.w);
    }
    __syncthreads();
    int u = t & 63, rq = t >> 6;
    #pragma unroll
    for (int pp = 0; pp < 4; ++pp) {
        int r = rq + 4 * pp;
        float gf = gl[r * 260 + u];
        float gi = gl[r * 260 + 64 + u];
        float go = gl[r * 260 + 128 + u];
        float gc = gl[r * 260 + 192 + u];
        float fg = 1.f / (1.f + __expf(-gf));
        float ig = 1.f / (1.f + __expf(-gi));
        float oo = 1.f / (1.f + __expf(-go));
        float ch = tanhf(gc);
        float cv = c[(base + r) * 64 + u];
        float ct = fg * cv + ig * ch;
        float ht = oo * fmaxf(ct, 0.f);
        out[OUTSZ + (base + r) * 64 + u] = ht;
        out[2 * OUTSZ + (base + r) * 64 + u] = ct;
    }
}

// ---------------- K5b: 16 rows/block (4x occupancy). Combine 8 partials -> xh, GEMM -> out ----------------
__global__ __launch_bounds__(256) void k5b(const float* __restrict__ ws, const float* __restrict__ bout,
                                           float* __restrict__ out)
{
    __shared__ float Al[16 * 132];
    int t = threadIdx.x;
    int base = blockIdx.x * 16;
    const float* ht = &out[OUTSZ];
    #pragma unroll
    for (int it = 0; it < 2; ++it) {
        int f = t + 256 * it;            // 0..511 = 16 rows x 32 float4-slots
        int r = f >> 5, q = f & 31;
        int k0 = q * 4;
        int row = base + r;
        float4 v;
        if (k0 < 64) {
            float4 s = make_float4(0.f, 0.f, 0.f, 0.f);
            float d = 0.f;
            #pragma unroll
            for (int jr = 0; jr < 8; ++jr) {
                float4 p = *(const float4*)&ws[WS_PN + ((size_t)jr * NT_ + row) * 64 + k0];
                s.x += p.x; s.y += p.y; s.z += p.z; s.w += p.w;
                d += ws[WS_PD + jr * NT_ + row];
            }
            float inv = 1.f / d;
            v.x = s.x * inv; v.x = v.x > 0.f ? v.x : expm1f(v.x);
            v.y = s.y * inv; v.y = v.y > 0.f ? v.y : expm1f(v.y);
            v.z = s.z * inv; v.z = v.z > 0.f ? v.z : expm1f(v.z);
            v.w = s.w * inv; v.w = v.w > 0.f ? v.w : expm1f(v.w);
        } else {
            v = *(const float4*)&ht[(size_t)row * 64 + (k0 - 64)];
        }
        *(float4*)&Al[r * 132 + k0] = v;
    }
    __syncthreads();
    int row = t >> 4, cg = t & 15;
    int o0 = cg * 4;
    const float* WT = &ws[WS_WOT];
    float4 acc = make_float4(0.f, 0.f, 0.f, 0.f);
    #pragma unroll 8
    for (int k = 0; k < 128; ++k) {
        float a = Al[row * 132 + k];                 // LDS broadcast within 16-lane group
        float4 wv = *(const float4*)&WT[k * 64 + o0];  // 32 KB WoutT: L1/L2-hot
        acc.x += a * wv.x; acc.y += a * wv.y; acc.z += a * wv.z; acc.w += a * wv.w;
    }
    float4 bo = *(const float4*)&bout[o0];
    float4 o;
    o.x = fmaxf(acc.x + bo.x, 0.f);
    o.y = fmaxf(acc.y + bo.y, 0.f);
    o.z = fmaxf(acc.z + bo.z, 0.f);
    o.w = fmaxf(acc.w + bo.w, 0.f);
    *(float4*)&out[(size_t)(base + row) * 64 + o0] = o;
}

extern "C" void kernel_launch(void* const* d_in, const int* in_sizes, int n_in,
                              void* d_out, int out_size, void* d_ws, size_t ws_size,
                              hipStream_t stream)
{
    const float* x    = (const float*)d_in[0];
    const float* adj  = (const float*)d_in[1];
    const float* c    = (const float*)d_in[2];
    const float* h    = (const float*)d_in[3];
    const float* W    = (const float*)d_in[4];
    const float* a    = (const float*)d_in[5];
    const float* Wf   = (const float*)d_in[6];
    const float* bWf  = (const float*)d_in[7];
    const float* Wi   = (const float*)d_in[8];
    const float* bWi  = (const float*)d_in[9];
    const float* Wo   = (const float*)d_in[10];
    const float* bWo  = (const float*)d_in[11];
    const float* Wc   = (const float*)d_in[12];
    const float* bWc  = (const float*)d_in[13];
    const float* Uf   = (const float*)d_in[14];
    const float* bUf  = (const float*)d_in[15];
    const float* Ui   = (const float*)d_in[16];
    const float* bUi  = (const float*)d_in[17];
    const float* Uo   = (const float*)d_in[18];
    const float* bUo  = (const float*)d_in[19];
    const float* Uc   = (const float*)d_in[20];
    const float* bUc  = (const float*)d_in[21];
    const float* Wout = (const float*)d_in[22];
    const float* bout = (const float*)d_in[23];
    float* out = (float*)d_out;
    float* ws  = (float*)d_ws;
    __bf16* whT = (__bf16*)out;   // WhT bf16 scratch in d_out segment 0; k5 overwrites last
    unsigned* mask = (unsigned*)&ws[WS_MASK];

    kpack<<<NT_ * (N_ / 32) / 256, 256, 0, stream>>>(adj, mask);   // 4096 blocks, linear stream
    k1_wh<<<417, 256, 0, stream>>>(x, W, a, ws, whT,
                                   Wf, Wi, Wo, Wc, Uf, Ui, Uo, Uc,
                                   bWf, bWi, bWo, bWc, bUf, bUi, bUo, bUc, Wout);
    k3_lstm<<<NT_ / 16, 256, 0, stream>>>(x, c, h, ws, out);
    k2v12<<<1024, 256, 0, stream>>>(mask, whT, ws);
    k5b<<<NT_ / 16, 256, 0, stream>>>(ws, bout, out);
}

// Round 16
// 85.653 us; speedup vs baseline: 1.1557x; 1.1367x over previous
//
#include <hip/hip_runtime.h>
#include <math.h>

#define B_ 8
#define N_ 2048
#define NT_ (B_*N_)          // 16384 rows
#define OUTSZ (NT_*64)       // 1048576 elements per output tensor

// ---- workspace layout (float offsets) ----
#define WS_ASRC  0
#define WS_ADST  (WS_ASRC + NT_)
#define WS_WT    (WS_ADST + NT_)         // [128][256] fused gate weights (transposed)
#define WS_BB    (WS_WT + 128*256)       // [256] combined gate bias
#define WS_WOT   (WS_BB + 256)           // [128][64] Wout transposed
#define WS_PD    (WS_WOT + 128*64)       // [8][NT_] partial denominators (f32)
#define WS_PN    (WS_PD + 8*NT_)         // bf16[8][NT_][64] partial numerators (16 MB)
// WhT bf16 [B][64][N] lives in d_out[0 .. 524288 floats) -- dead until k5 overwrites.

typedef float f32x4 __attribute__((ext_vector_type(4)));
typedef __bf16 bf16x8 __attribute__((ext_vector_type(8)));
typedef __bf16 bf16x4 __attribute__((ext_vector_type(4)));

__device__ __forceinline__ float lrelu2(float x) { return x > 0.f ? x : 2.f * x; }
__device__ __forceinline__ float f4get(const float4& v, int k) { return k==0?v.x:(k==1?v.y:(k==2?v.z:v.w)); }

// ---------------- K1 (+fused weight prep): Wh = x@W -> WhT bf16, a_src/a_dst ----------------
__global__ __launch_bounds__(256) void k1_wh(const float* __restrict__ x, const float* __restrict__ W,
                                             const float* __restrict__ a, float* __restrict__ ws,
                                             __bf16* __restrict__ whT,
                                             const float* Wf, const float* Wi, const float* Wo, const float* Wc,
                                             const float* Uf, const float* Ui, const float* Uo, const float* Uc,
                                             const float* bWf, const float* bWi, const float* bWo, const float* bWc,
                                             const float* bUf, const float* bUi, const float* bUo, const float* bUc,
                                             const float* Wout)
{
    __shared__ float xl[64 * 68];
    __shared__ float Wl[64 * 68];
    int t = threadIdx.x;
    if (blockIdx.x >= 256) {
        int idx = (blockIdx.x - 256) * 256 + t;
        if (idx < 128 * 256) {
            int k = idx >> 8, o = idx & 255;
            int g = o >> 6, u = o & 63;
            const float* Wg = (g == 0) ? Wf : (g == 1) ? Wi : (g == 2) ? Wo : Wc;
            const float* Ug = (g == 0) ? Uf : (g == 1) ? Ui : (g == 2) ? Uo : Uc;
            ws[WS_WT + idx] = (k < 64) ? Wg[u * 64 + k] : Ug[u * 64 + (k - 64)];
        } else if (idx < 128 * 256 + 256) {
            int o = idx - 128 * 256;
            int g = o >> 6, u = o & 63;
            const float* bW = (g == 0) ? bWf : (g == 1) ? bWi : (g == 2) ? bWo : bWc;
            const float* bU = (g == 0) ? bUf : (g == 1) ? bUi : (g == 2) ? bUo : bUc;
            ws[WS_BB + o] = bW[u] + bU[u];
        } else if (idx < 128 * 256 + 256 + 128 * 64) {
            int j = idx - (128 * 256 + 256);
            int k = j >> 6, u = j & 63;
            ws[WS_WOT + j] = Wout[u * 128 + k];   // WoutT[k][u]
        }
        return;
    }
    int i0 = blockIdx.x * 64;
    #pragma unroll
    for (int it = 0; it < 4; ++it) {
        int f = t + 256 * it;
        int r = f >> 4, q = f & 15;
        *(float4*)&xl[r * 68 + q * 4] = *(const float4*)&x[i0 * 64 + f * 4];
        *(float4*)&Wl[r * 68 + q * 4] = *(const float4*)&W[f * 4];
    }
    __syncthreads();
    int cg = t & 15, rg = t >> 4;
    int c0 = cg * 4, r0 = rg * 4;
    float acc[4][4] = {};
    #pragma unroll
    for (int d0 = 0; d0 < 64; d0 += 4) {
        float4 wv[4], xv[4];
        #pragma unroll
        for (int k = 0; k < 4; ++k) wv[k] = *(float4*)&Wl[(d0 + k) * 68 + c0];
        #pragma unroll
        for (int ri = 0; ri < 4; ++ri) xv[ri] = *(float4*)&xl[(r0 + ri) * 68 + d0];
        #pragma unroll
        for (int ri = 0; ri < 4; ++ri)
            #pragma unroll
            for (int k = 0; k < 4; ++k) {
                float xs = f4get(xv[ri], k);
                acc[ri][0] += xs * wv[k].x; acc[ri][1] += xs * wv[k].y;
                acc[ri][2] += xs * wv[k].z; acc[ri][3] += xs * wv[k].w;
            }
    }
    int b = i0 >> 11;
    int rowb0 = (i0 & 2047) + r0;
    #pragma unroll
    for (int cj = 0; cj < 4; ++cj) {
        bf16x4 v;
        v[0] = (__bf16)acc[0][cj]; v[1] = (__bf16)acc[1][cj];
        v[2] = (__bf16)acc[2][cj]; v[3] = (__bf16)acc[3][cj];
        *(bf16x4*)&whT[((size_t)(b * 64 + c0 + cj)) * N_ + rowb0] = v;
    }
    float4 a0 = *(const float4*)&a[c0];
    float4 a1 = *(const float4*)&a[64 + c0];
    #pragma unroll
    for (int ri = 0; ri < 4; ++ri) {
        int row = i0 + r0 + ri;
        float s0 = acc[ri][0]*a0.x + acc[ri][1]*a0.y + acc[ri][2]*a0.z + acc[ri][3]*a0.w;
        float s1 = acc[ri][0]*a1.x + acc[ri][1]*a1.y + acc[ri][2]*a1.z + acc[ri][3]*a1.w;
        #pragma unroll
        for (int m = 1; m < 16; m <<= 1) { s0 += __shfl_xor(s0, m, 64); s1 += __shfl_xor(s1, m, 64); }
        if (cg == 0) { ws[WS_ASRC + row] = s0; ws[WS_ADST + row] = s1; }
    }
}

// ---------------- K2v10b: R13's k2v10 with bf16 partial numerators ----------------
// Block = (jr of 8, 128-row slab), 4 waves x fixed 64-j window; B-frags + Ej register-resident.
// adj staged coalesced -> regs -> bf16 -> LDS double buffer; A-frags via ds_read_b128.
// Per-batch gmax computed per-block (no atomics/memset). PN written as bf16 (halves traffic).
__global__ __launch_bounds__(256) void k2v10(const float* __restrict__ adj,
                                             const __bf16* __restrict__ whT,
                                             float* __restrict__ ws)
{
    __shared__ __bf16 adjt[2][16][268];
    __shared__ float lsa[4][16][68];
    __shared__ float lsd[4][16];
    __shared__ float gred[4];
    int tid = threadIdx.x;
    int lane = tid & 63, w = tid >> 6;        // 4 waves
    int r = lane & 15, g = lane >> 4;
    int jr = blockIdx.x & 7;
    int rslab = blockIdx.x >> 3;              // 0..127
    int b = rslab >> 4;
    int row_base = rslab * 128;
    int jbeg = jr * 256 + w * 64;

    // per-batch gmax: block-local reduce over ADST (L2-resident)
    {
        float gm = -3.0e38f;
        for (int i = tid; i < N_; i += 256) gm = fmaxf(gm, ws[WS_ADST + b * N_ + i]);
        #pragma unroll
        for (int m_ = 1; m_ < 64; m_ <<= 1) gm = fmaxf(gm, __shfl_xor(gm, m_, 64));
        if (lane == 0) gred[w] = gm;
    }
    __syncthreads();
    float gmax = fmaxf(fmaxf(gred[0], gred[1]), fmaxf(gred[2], gred[3]));

    // loop-invariant B-frags: lane -> col h = n*16 + r, k-window = ks*32 + g*8
    bf16x8 bfr[2][4];
    #pragma unroll
    for (int ks = 0; ks < 2; ++ks)
        #pragma unroll
        for (int n = 0; n < 4; ++n)
            bfr[ks][n] = *(const bf16x8*)&whT[(size_t)(b * 64 + n * 16 + r) * N_ + jbeg + ks * 32 + g * 8];
    // loop-invariant Ej = exp(adst_j) registers
    float ejr[2][8];
    #pragma unroll
    for (int ks = 0; ks < 2; ++ks) {
        float4 d0 = *(const float4*)&ws[WS_ADST + b * N_ + jbeg + ks * 32 + g * 8];
        float4 d1 = *(const float4*)&ws[WS_ADST + b * N_ + jbeg + ks * 32 + g * 8 + 4];
        ejr[ks][0]=__expf(d0.x); ejr[ks][1]=__expf(d0.y); ejr[ks][2]=__expf(d0.z); ejr[ks][3]=__expf(d0.w);
        ejr[ks][4]=__expf(d1.x); ejr[ks][5]=__expf(d1.y); ejr[ks][6]=__expf(d1.z); ejr[ks][7]=__expf(d1.w);
    }
    // all 8 per-tile asrc scalars hoisted (statically indexed)
    float asv8[8];
    #pragma unroll
    for (int tt = 0; tt < 8; ++tt)
        asv8[tt] = ws[WS_ASRC + row_base + tt * 16 + r];

    f32x4 sreg[2][4];

#define SLOAD(T, S)                                                                        \
    {                                                                                      \
        _Pragma("unroll")                                                                  \
        for (int i = 0; i < 4; ++i)                                                        \
            sreg[S][i] = *(const f32x4*)&adj[(size_t)(row_base + (T) * 16 + w * 4 + i) * N_ \
                                             + jr * 256 + lane * 4];                       \
    }
#define SWRITE(T, S)                                                                       \
    {                                                                                      \
        _Pragma("unroll")                                                                  \
        for (int i = 0; i < 4; ++i) {                                                      \
            bf16x4 bv;                                                                     \
            bv[0] = (__bf16)sreg[S][i][0]; bv[1] = (__bf16)sreg[S][i][1];                  \
            bv[2] = (__bf16)sreg[S][i][2]; bv[3] = (__bf16)sreg[S][i][3];                  \
            *(bf16x4*)&adjt[(T) & 1][w * 4 + i][lane * 4] = bv;                            \
        }                                                                                  \
    }

    // prologue: tile 0 into LDS, tile 1 into regs
    SLOAD(0, 0);
    SWRITE(0, 0);
    SLOAD(1, 1);
    asm volatile("s_waitcnt lgkmcnt(0)" ::: "memory");
    __builtin_amdgcn_s_barrier();
    asm volatile("" ::: "memory");

    __bf16* pn = (__bf16*)&ws[WS_PN];

    #pragma unroll
    for (int t = 0; t < 8; ++t) {
        const int s = t & 1;
        if (t + 2 < 8) { SLOAD(t + 2, s); }        // sreg slot s free: tile t already in LDS
        float as = asv8[t];
        float M  = lrelu2(as + gmax);
        float c1 = __expf(as - M);
        float c2 = __expf(2.f * as - M);
        float thr = __expf(-as);
        // ---- compute tile t from LDS ----
        f32x4 acc[4] = {{0.f,0.f,0.f,0.f},{0.f,0.f,0.f,0.f},{0.f,0.f,0.f,0.f},{0.f,0.f,0.f,0.f}};
        float dsum = 0.f;
        #pragma unroll
        for (int ks = 0; ks < 2; ++ks) {
            bf16x8 at = *(const bf16x8*)&adjt[s][r][w * 64 + ks * 32 + g * 8];
            bf16x8 af;
            float ds_ = 0.f;
            #pragma unroll
            for (int e = 0; e < 8; ++e) {
                float avv = (float)at[e];
                float E = ejr[ks][e];
                float p = (E > thr) ? c1 * E : (c2 * E) * E;
                p = (avv > 0.f) ? p : 0.f;
                ds_ += p;
                af[e] = (__bf16)p;
            }
            dsum += ds_;
            #pragma unroll
            for (int n = 0; n < 4; ++n)
                acc[n] = __builtin_amdgcn_mfma_f32_16x16x32_bf16(af, bfr[ks][n], acc[n], 0, 0, 0);
        }
        dsum += __shfl_xor(dsum, 16, 64);
        dsum += __shfl_xor(dsum, 32, 64);
        // wave partial -> LDS
        #pragma unroll
        for (int n = 0; n < 4; ++n)
            #pragma unroll
            for (int i = 0; i < 4; ++i)
                lsa[w][g * 4 + i][n * 16 + r] = acc[n][i];
        if (g == 0) lsd[w][r] = dsum;
        // stage tile t+1 into the other LDS buffer
        if (t + 1 < 8) { SWRITE(t + 1, s ^ 1); }
        // raw barrier 1: lsa + adjt[(t+1)&1] visible; global loads (t+2) stay in flight
        asm volatile("s_waitcnt lgkmcnt(0)" ::: "memory");
        __builtin_amdgcn_s_barrier();
        asm volatile("" ::: "memory");
        // combine 4 wave-slices -> global bf16 partial (jr slice)
        {
            int rl = tid >> 4, h0 = (tid & 15) * 4;
            float4 sv = make_float4(0.f, 0.f, 0.f, 0.f);
            #pragma unroll
            for (int w2 = 0; w2 < 4; ++w2) {
                float4 q = *(const float4*)&lsa[w2][rl][h0];
                sv.x += q.x; sv.y += q.y; sv.z += q.z; sv.w += q.w;
            }
            int row0 = row_base + t * 16;
            bf16x4 bv;
            bv[0] = (__bf16)sv.x; bv[1] = (__bf16)sv.y; bv[2] = (__bf16)sv.z; bv[3] = (__bf16)sv.w;
            *(bf16x4*)&pn[((size_t)jr * NT_ + row0 + rl) * 64 + h0] = bv;
            if (tid < 16)
                ws[WS_PD + jr * NT_ + row0 + tid] =
                    lsd[0][tid] + lsd[1][tid] + lsd[2][tid] + lsd[3][tid];
        }
        // raw barrier 2: combine reads done before next tile rewrites lsa
        asm volatile("s_waitcnt lgkmcnt(0)" ::: "memory");
        __builtin_amdgcn_s_barrier();
        asm volatile("" ::: "memory");
    }
#undef SLOAD
#undef SWRITE
}

// ---------------- K3: LSTM gates + cell update. 16 rows/block ----------------
__global__ __launch_bounds__(256) void k3_lstm(const float* __restrict__ x, const float* __restrict__ c,
                                               const float* __restrict__ h, const float* __restrict__ ws,
                                               float* __restrict__ out)
{
    __shared__ float Al[16 * 132];   // [row][k]: k<64 = h, k>=64 = x
    __shared__ float gl[16 * 260];   // gate pre-activations [row][256]
    int t = threadIdx.x;
    int base = blockIdx.x * 16;
    {
        int r = t >> 4, k0 = (t & 15) * 8;
        const float* src = (k0 < 64) ? &h[(base + r) * 64 + k0] : &x[(base + r) * 64 + (k0 - 64)];
        *(float4*)&Al[r * 132 + k0]     = *(const float4*)&src[0];
        *(float4*)&Al[r * 132 + k0 + 4] = *(const float4*)&src[4];
    }
    __syncthreads();
    int og = t & 63, rg = t >> 6;
    int o0 = og * 4;
    const float* WT = &ws[WS_WT];
    float acc[4][4] = {};
    #pragma unroll
    for (int k0 = 0; k0 < 128; k0 += 4) {
        float4 wv[4], av[4];
        #pragma unroll
        for (int kk = 0; kk < 4; ++kk) wv[kk] = *(const float4*)&WT[(k0 + kk) * 256 + o0];
        #pragma unroll
        for (int rr = 0; rr < 4; ++rr) av[rr] = *(float4*)&Al[(rg + 4 * rr) * 132 + k0];
        #pragma unroll
        for (int rr = 0; rr < 4; ++rr)
            #pragma unroll
            for (int kk = 0; kk < 4; ++kk) {
                float as = f4get(av[rr], kk);
                acc[rr][0] += as * wv[kk].x; acc[rr][1] += as * wv[kk].y;
                acc[rr][2] += as * wv[kk].z; acc[rr][3] += as * wv[kk].w;
            }
    }
    float4 bbv = *(const float4*)&ws[WS_BB + o0];
    #pragma unroll
    for (int rr = 0; rr < 4; ++rr) {
        int r = rg + 4 * rr;
        *(float4*)&gl[r * 260 + o0] = make_float4(acc[rr][0] + bbv.x, acc[rr][1] + bbv.y,
                                                  acc[rr][2] + bbv.z, acc[rr][3] + bbv.w);
    }
    __syncthreads();
    int u = t & 63, rq = t >> 6;
    #pragma unroll
    for (int pp = 0; pp < 4; ++pp) {
        int r = rq + 4 * pp;
        float gf = gl[r * 260 + u];
        float gi = gl[r * 260 + 64 + u];
        float go = gl[r * 260 + 128 + u];
        float gc = gl[r * 260 + 192 + u];
        float fg = 1.f / (1.f + __expf(-gf));
        float ig = 1.f / (1.f + __expf(-gi));
        float oo = 1.f / (1.f + __expf(-go));
        float ch = tanhf(gc);
        float cv = c[(base + r) * 64 + u];
        float ct = fg * cv + ig * ch;
        float ht = oo * fmaxf(ct, 0.f);
        out[OUTSZ + (base + r) * 64 + u] = ht;
        out[2 * OUTSZ + (base + r) * 64 + u] = ct;
    }
}

// ---------------- K5b: 16 rows/block (4 blocks/CU). Combine 8 bf16 partials -> xh, GEMM -> out ----------------
__global__ __launch_bounds__(256) void k5b(const float* __restrict__ ws, const float* __restrict__ bout,
                                           float* __restrict__ out)
{
    __shared__ float Al[16 * 132];
    int t = threadIdx.x;
    int base = blockIdx.x * 16;
    const float* ht = &out[OUTSZ];
    const __bf16* pn = (const __bf16*)&ws[WS_PN];
    #pragma unroll
    for (int it = 0; it < 2; ++it) {
        int f = t + 256 * it;            // 0..511 = 16 rows x 32 float4-slots
        int r = f >> 5, q = f & 31;
        int k0 = q * 4;
        int row = base + r;
        float4 v;
        if (k0 < 64) {
            float4 s = make_float4(0.f, 0.f, 0.f, 0.f);
            float d = 0.f;
            #pragma unroll
            for (int jr = 0; jr < 8; ++jr) {
                bf16x4 p = *(const bf16x4*)&pn[((size_t)jr * NT_ + row) * 64 + k0];
                s.x += (float)p[0]; s.y += (float)p[1]; s.z += (float)p[2]; s.w += (float)p[3];
                d += ws[WS_PD + jr * NT_ + row];
            }
            float inv = 1.f / d;
            v.x = s.x * inv; v.x = v.x > 0.f ? v.x : expm1f(v.x);
            v.y = s.y * inv; v.y = v.y > 0.f ? v.y : expm1f(v.y);
            v.z = s.z * inv; v.z = v.z > 0.f ? v.z : expm1f(v.z);
            v.w = s.w * inv; v.w = v.w > 0.f ? v.w : expm1f(v.w);
        } else {
            v = *(const float4*)&ht[(size_t)row * 64 + (k0 - 64)];
        }
        *(float4*)&Al[r * 132 + k0] = v;
    }
    __syncthreads();
    int row = t >> 4, cg = t & 15;
    int o0 = cg * 4;
    const float* WT = &ws[WS_WOT];
    float4 acc = make_float4(0.f, 0.f, 0.f, 0.f);
    #pragma unroll 8
    for (int k = 0; k < 128; ++k) {
        float a = Al[row * 132 + k];                   // LDS broadcast within 16-lane group
        float4 wv = *(const float4*)&WT[k * 64 + o0];  // 32 KB WoutT: L2-hot
        acc.x += a * wv.x; acc.y += a * wv.y; acc.z += a * wv.z; acc.w += a * wv.w;
    }
    float4 bo = *(const float4*)&bout[o0];
    float4 o;
    o.x = fmaxf(acc.x + bo.x, 0.f);
    o.y = fmaxf(acc.y + bo.y, 0.f);
    o.z = fmaxf(acc.z + bo.z, 0.f);
    o.w = fmaxf(acc.w + bo.w, 0.f);
    *(float4*)&out[(size_t)(base + row) * 64 + o0] = o;
}

extern "C" void kernel_launch(void* const* d_in, const int* in_sizes, int n_in,
                              void* d_out, int out_size, void* d_ws, size_t ws_size,
                              hipStream_t stream)
{
    const float* x    = (const float*)d_in[0];
    const float* adj  = (const float*)d_in[1];
    const float* c    = (const float*)d_in[2];
    const float* h    = (const float*)d_in[3];
    const float* W    = (const float*)d_in[4];
    const float* a    = (const float*)d_in[5];
    const float* Wf   = (const float*)d_in[6];
    const float* bWf  = (const float*)d_in[7];
    const float* Wi   = (const float*)d_in[8];
    const float* bWi  = (const float*)d_in[9];
    const float* Wo   = (const float*)d_in[10];
    const float* bWo  = (const float*)d_in[11];
    const float* Wc   = (const float*)d_in[12];
    const float* bWc  = (const float*)d_in[13];
    const float* Uf   = (const float*)d_in[14];
    const float* bUf  = (const float*)d_in[15];
    const float* Ui   = (const float*)d_in[16];
    const float* bUi  = (const float*)d_in[17];
    const float* Uo   = (const float*)d_in[18];
    const float* bUo  = (const float*)d_in[19];
    const float* Uc   = (const float*)d_in[20];
    const float* bUc  = (const float*)d_in[21];
    const float* Wout = (const float*)d_in[22];
    const float* bout = (const float*)d_in[23];
    float* out = (float*)d_out;
    float* ws  = (float*)d_ws;
    __bf16* whT = (__bf16*)out;   // WhT bf16 scratch in d_out segment 0; k5 overwrites last

    k1_wh<<<417, 256, 0, stream>>>(x, W, a, ws, whT,
                                   Wf, Wi, Wo, Wc, Uf, Ui, Uo, Uc,
                                   bWf, bWi, bWo, bWc, bUf, bUi, bUo, bUc, Wout);
    k3_lstm<<<NT_ / 16, 256, 0, stream>>>(x, c, h, ws, out);
    k2v10<<<1024, 256, 0, stream>>>(adj, whT, ws);
    k5b<<<NT_ / 16, 256, 0, stream>>>(ws, bout, out);
}